// Round 11
// baseline (839.437 us; speedup 1.0000x reference)
//
#include <hip/hip_runtime.h>

#define LP 40    // k_support LDS row stride (shorts)

typedef __attribute__((ext_vector_type(8))) short short8;
typedef __attribute__((ext_vector_type(4))) short short4t;
typedef __attribute__((ext_vector_type(4))) float f32x4;

__device__ __forceinline__ short f2bf(float f) {
  unsigned u = __builtin_bit_cast(unsigned, f);
  u += 0x7FFFu + ((u >> 16) & 1u);   // round-to-nearest-even
  return (short)(u >> 16);
}

__device__ __forceinline__ float lrelu(float v) { return v >= 0.f ? v : 0.2f * v; }

// ---------------- Kernel 0: wT bf16 [512][512]  (wt[n][c] = w[c][n]) ----------------
__global__ __launch_bounds__(256) void k_wt(const float* __restrict__ w,
                                            short* __restrict__ wt) {
  __shared__ float t[64][65];
  int c0 = (blockIdx.x & 7) * 64;
  int n0 = (blockIdx.x >> 3) * 64;
  int r  = threadIdx.x >> 4;
  int q4 = (threadIdx.x & 15) * 4;
  for (int i = 0; i < 4; i++) {
    int c = r + i * 16;
    f32x4 v = *(const f32x4*)(w + (size_t)(c0 + c) * 512 + (n0 + q4));
    t[c][q4 + 0] = v[0]; t[c][q4 + 1] = v[1]; t[c][q4 + 2] = v[2]; t[c][q4 + 3] = v[3];
  }
  __syncthreads();
  for (int i = 0; i < 4; i++) {
    int n = r + i * 16;
    short4t o;
    for (int j = 0; j < 4; j++) o[j] = f2bf(t[q4 + j][n]);
    *(short4t*)(wt + (size_t)(n0 + n) * 512 + (c0 + q4)) = o;
  }
}

// ------------- Kernel 1: supportT bf16 [512][8192] = (inputs @ w + b)^T -------------
__global__ __launch_bounds__(512, 2) void k_support(const float* __restrict__ inp,
                                                    const short* __restrict__ wt,
                                                    const float* __restrict__ bias,
                                                    short* __restrict__ sup) {
  __shared__ __align__(16) short As[512 * LP];
  __shared__ __align__(16) short Bs[64 * LP];
  const int tid = threadIdx.x;
  const int m0 = blockIdx.x * 64;
  const int wave = tid >> 6, lane = tid & 63;
  const int wn = wave >> 1, wm = wave & 1;
  const int lr = lane & 15, lk = lane >> 4;
  const int bm = tid >> 3, bk = (tid & 7) * 4;
  f32x4 acc[8][2] = {};
  short8 ar[4]; f32x4 br;
  auto loadA = [&](int s) {
    const short* p = wt + (size_t)tid * 512 + s * 32;
    ar[0] = *(const short8*)(p);      ar[1] = *(const short8*)(p + 8);
    ar[2] = *(const short8*)(p + 16); ar[3] = *(const short8*)(p + 24);
  };
  auto loadB = [&](int s) {
    br = *(const f32x4*)(inp + (size_t)(m0 + bm) * 512 + s * 32 + bk);
  };
  loadA(0); loadB(0);
  for (int s = 0; s < 16; s++) {
    short* ad = As + tid * LP;
    *(short8*)(ad) = ar[0]; *(short8*)(ad + 8) = ar[1];
    *(short8*)(ad + 16) = ar[2]; *(short8*)(ad + 24) = ar[3];
    short4t bo;
    for (int j = 0; j < 4; j++) bo[j] = f2bf(br[j]);
    *(short4t*)(Bs + bm * LP + bk) = bo;
    __syncthreads();
    if (s + 1 < 16) { loadA(s + 1); loadB(s + 1); }
    short8 af[8], bfr[2];
    for (int nf = 0; nf < 8; nf++)
      af[nf] = *(const short8*)(As + (wn * 128 + nf * 16 + lr) * LP + lk * 8);
    for (int mf = 0; mf < 2; mf++)
      bfr[mf] = *(const short8*)(Bs + (wm * 32 + mf * 16 + lr) * LP + lk * 8);
    for (int nf = 0; nf < 8; nf++)
      for (int mf = 0; mf < 2; mf++)
        acc[nf][mf] = __builtin_amdgcn_mfma_f32_16x16x32_bf16(af[nf], bfr[mf], acc[nf][mf], 0, 0, 0);
    __syncthreads();
  }
  for (int nf = 0; nf < 8; nf++) {
    int nb = wn * 128 + nf * 16 + lk * 4;
    for (int mf = 0; mf < 2; mf++) {
      int m = m0 + wm * 32 + mf * 16 + lr;
      for (int j = 0; j < 4; j++) {
        int n = nb + j;
        sup[(size_t)n * 8192 + m] = f2bf(acc[nf][mf][j] + bias[n]);
      }
    }
  }
}

// ===== Kernel 2: WAVE-AUTONOMOUS — no LDS, no barriers, no asm. Each wave loads
// ===== its own MFMA B-fragment from the 4 adj mats, combines in registers, MFMAs.
// ===== 8 waves = 4 m-waves(16 rows) x 2 n-waves(256 ch). BM=64, BN=512, BK=32.
// ===== Structurally = P4 probe (5.65 TB/s) + register-local compute.
template <int KSPLIT>
__global__ __launch_bounds__(512, 2) void k_main(const float* __restrict__ adj,
                                                 const float* __restrict__ att,
                                                 const short* __restrict__ sup,
                                                 float* __restrict__ part,
                                                 float* __restrict__ outp) {
  constexpr int KCH = 8192 / KSPLIT;
  constexpr int NSTEPS = KCH / 32;
  const int tid = threadIdx.x;
  const int b = blockIdx.x;
  const int xpk = 8 / KSPLIT;
  const int xcd = b & 7;
  const int kc = xcd / xpk;                 // kc pinned per XCD group -> sup L2-warm
  const int m0 = ((b >> 3) * xpk + (xcd % xpk)) * 64;
  const int kbase = kc * KCH;
  const float t0 = att[0], t1 = att[1], t2 = att[2], t3 = att[3];
  const int w = tid >> 6, lane = tid & 63;
  const int lr = lane & 15, lk = lane >> 4;
  const int nw = w & 1, mw = w >> 1;        // adjacent waves share m-slice (L1 reuse)
  // B-fragment source: lane holds combined[k=lk*8+j][col=m0+mw*16+lr]
  const float* ab = adj + (size_t)(m0 + mw * 16 + lr) * 8192 + kbase + lk * 8;
  // A-fragment source: lane holds sup[row=nw*256+nf*16+lr][k=lk*8+j]
  const short* sb = sup + (size_t)(nw * 256 + lr) * 8192 + kbase + lk * 8;
  f32x4 acc[16] = {};                       // 64 VGPR

  for (int s = 0; s < NSTEPS; s++) {
    const float* p = ab + s * 32;
    // 8 global loads: 2 x f32x4 per mat (k..k+3, k+4..k+7), 4 mats
    f32x4 b0a = __builtin_nontemporal_load((const f32x4*)(p));
    f32x4 b0b = __builtin_nontemporal_load((const f32x4*)(p + 4));
    f32x4 b1a = __builtin_nontemporal_load((const f32x4*)(p + (1ull << 26)));
    f32x4 b1b = __builtin_nontemporal_load((const f32x4*)(p + (1ull << 26) + 4));
    f32x4 b2a = __builtin_nontemporal_load((const f32x4*)(p + (2ull << 26)));
    f32x4 b2b = __builtin_nontemporal_load((const f32x4*)(p + (2ull << 26) + 4));
    f32x4 b3a = __builtin_nontemporal_load((const f32x4*)(p + (3ull << 26)));
    f32x4 b3b = __builtin_nontemporal_load((const f32x4*)(p + (3ull << 26) + 4));
    // A-fragments (sup bf16, L2/L1-resident)
    short8 af[16];
#pragma unroll
    for (int nf = 0; nf < 16; nf++)
      af[nf] = *(const short8*)(sb + (size_t)(nf * 16) * 8192 + s * 32);
    // combine 4 mats with att weights -> bf16 B-fragment
    f32x4 cA, cB;
#pragma unroll
    for (int e = 0; e < 4; e++) {
      cA[e] = t0 * b0a[e] + t1 * b1a[e] + t2 * b2a[e] + t3 * b3a[e];
      cB[e] = t0 * b0b[e] + t1 * b1b[e] + t2 * b2b[e] + t3 * b3b[e];
    }
    short8 bfr;
#pragma unroll
    for (int e = 0; e < 4; e++) { bfr[e] = f2bf(cA[e]); bfr[4 + e] = f2bf(cB[e]); }
    // 16 MFMAs: independent acc chains, B-frag reused 16x
#pragma unroll
    for (int nf = 0; nf < 16; nf++)
      acc[nf] = __builtin_amdgcn_mfma_f32_16x16x32_bf16(af[nf], bfr, acc[nf], 0, 0, 0);
  }

#pragma unroll
  for (int nf = 0; nf < 16; nf++) {
    int n = nw * 256 + nf * 16 + lk * 4;
    int m = m0 + mw * 16 + lr;
    f32x4 v = acc[nf];
    if (KSPLIT == 1) {
      for (int j = 0; j < 4; j++) v[j] = lrelu(v[j]);
      __builtin_nontemporal_store(v, (f32x4*)(outp + (size_t)m * 512 + n));
    } else {
      __builtin_nontemporal_store(v, (f32x4*)(part + ((size_t)kc << 22) + (size_t)m * 512 + n));
    }
  }
}

// ---------------- Kernel 3: reduce K-split partials + LeakyReLU ----------------
__global__ __launch_bounds__(256) void k_reduce(const float* __restrict__ part,
                                                float* __restrict__ outp, int ksplit) {
  const size_t total = (size_t)8192 * 512 / 4;
  for (size_t i = (size_t)blockIdx.x * 256 + threadIdx.x; i < total;
       i += (size_t)gridDim.x * 256) {
    f32x4 a = __builtin_nontemporal_load((const f32x4*)(part + i * 4));
    for (int k = 1; k < ksplit; k++) {
      f32x4 bv = __builtin_nontemporal_load((const f32x4*)(part + ((size_t)k << 22) + i * 4));
      for (int j = 0; j < 4; j++) a[j] += bv[j];
    }
    f32x4 v;
    for (int j = 0; j < 4; j++) v[j] = lrelu(a[j]);
    __builtin_nontemporal_store(v, (f32x4*)(outp + i * 4));
  }
}

extern "C" void kernel_launch(void* const* d_in, const int* in_sizes, int n_in,
                              void* d_out, int out_size, void* d_ws, size_t ws_size,
                              hipStream_t stream) {
  const float* inputs = (const float*)d_in[0];
  const float* adj    = (const float*)d_in[1];
  const float* att    = (const float*)d_in[2];
  const float* w      = (const float*)d_in[3];
  const float* bias   = (const float*)d_in[4];
  float* outp = (float*)d_out;

  char* ws = (char*)d_ws;
  short* sup  = (short*)(ws);                 // 8 MB  supportT bf16 [512][8192]
  short* wt   = (short*)(ws + (8u << 20));    // 512 KB wT bf16 [512][512]
  float* part = (float*)(ws + (9u << 20));    // ksplit x 16 MB fp32 partials

  const size_t base = (9ull << 20), psz = (1ull << 24);

  k_wt<<<64, 256, 0, stream>>>(w, wt);
  k_support<<<128, 512, 0, stream>>>(inputs, wt, bias, sup);

  if (ws_size >= base + 2 * psz) {
    k_main<2><<<256, 512, 0, stream>>>(adj, att, sup, part, outp);
    k_reduce<<<1024, 256, 0, stream>>>(part, outp, 2);
  } else {
    k_main<1><<<128, 512, 0, stream>>>(adj, att, sup, part, outp);
  }
}

// Round 12
// 350.149 us; speedup vs baseline: 2.3974x; 2.3974x over previous
//
#include <hip/hip_runtime.h>

#define LP  40    // k_support LDS row stride (shorts)
#define LPB 40    // fallback k_main64 Bs row stride (shorts)

typedef __attribute__((ext_vector_type(8))) short short8;
typedef __attribute__((ext_vector_type(4))) short short4t;
typedef __attribute__((ext_vector_type(4))) float f32x4;

__device__ __forceinline__ short f2bf(float f) {
  unsigned u = __builtin_bit_cast(unsigned, f);
  u += 0x7FFFu + ((u >> 16) & 1u);   // round-to-nearest-even
  return (short)(u >> 16);
}

__device__ __forceinline__ float lrelu(float v) { return v >= 0.f ? v : 0.2f * v; }

// ---------------- Kernel 0: wT bf16 [512][512]  (wt[n][c] = w[c][n]) ----------------
__global__ __launch_bounds__(256) void k_wt(const float* __restrict__ w,
                                            short* __restrict__ wt) {
  __shared__ float t[64][65];
  int c0 = (blockIdx.x & 7) * 64;
  int n0 = (blockIdx.x >> 3) * 64;
  int r  = threadIdx.x >> 4;
  int q4 = (threadIdx.x & 15) * 4;
  for (int i = 0; i < 4; i++) {
    int c = r + i * 16;
    f32x4 v = *(const f32x4*)(w + (size_t)(c0 + c) * 512 + (n0 + q4));
    t[c][q4 + 0] = v[0]; t[c][q4 + 1] = v[1]; t[c][q4 + 2] = v[2]; t[c][q4 + 3] = v[3];
  }
  __syncthreads();
  for (int i = 0; i < 4; i++) {
    int n = r + i * 16;
    short4t o;
    for (int j = 0; j < 4; j++) o[j] = f2bf(t[q4 + j][n]);
    *(short4t*)(wt + (size_t)(n0 + n) * 512 + (c0 + q4)) = o;
  }
}

// ------------- Kernel 1: supportT bf16 [512][8192] = (inputs @ w + b)^T -------------
__global__ __launch_bounds__(512, 2) void k_support(const float* __restrict__ inp,
                                                    const short* __restrict__ wt,
                                                    const float* __restrict__ bias,
                                                    short* __restrict__ sup) {
  __shared__ __align__(16) short As[512 * LP];
  __shared__ __align__(16) short Bs[64 * LP];
  const int tid = threadIdx.x;
  const int m0 = blockIdx.x * 64;
  const int wave = tid >> 6, lane = tid & 63;
  const int wn = wave >> 1, wm = wave & 1;
  const int lr = lane & 15, lk = lane >> 4;
  const int bm = tid >> 3, bk = (tid & 7) * 4;
  f32x4 acc[8][2] = {};
  short8 ar[4]; f32x4 br;
  auto loadA = [&](int s) {
    const short* p = wt + (size_t)tid * 512 + s * 32;
    ar[0] = *(const short8*)(p);      ar[1] = *(const short8*)(p + 8);
    ar[2] = *(const short8*)(p + 16); ar[3] = *(const short8*)(p + 24);
  };
  auto loadB = [&](int s) {
    br = *(const f32x4*)(inp + (size_t)(m0 + bm) * 512 + s * 32 + bk);
  };
  loadA(0); loadB(0);
  for (int s = 0; s < 16; s++) {
    short* ad = As + tid * LP;
    *(short8*)(ad) = ar[0]; *(short8*)(ad + 8) = ar[1];
    *(short8*)(ad + 16) = ar[2]; *(short8*)(ad + 24) = ar[3];
    short4t bo;
    for (int j = 0; j < 4; j++) bo[j] = f2bf(br[j]);
    *(short4t*)(Bs + bm * LP + bk) = bo;
    __syncthreads();
    if (s + 1 < 16) { loadA(s + 1); loadB(s + 1); }
    short8 af[8], bfr[2];
    for (int nf = 0; nf < 8; nf++)
      af[nf] = *(const short8*)(As + (wn * 128 + nf * 16 + lr) * LP + lk * 8);
    for (int mf = 0; mf < 2; mf++)
      bfr[mf] = *(const short8*)(Bs + (wm * 32 + mf * 16 + lr) * LP + lk * 8);
    for (int nf = 0; nf < 8; nf++)
      for (int mf = 0; mf < 2; mf++)
        acc[nf][mf] = __builtin_amdgcn_mfma_f32_16x16x32_bf16(af[nf], bfr[mf], acc[nf][mf], 0, 0, 0);
    __syncthreads();
  }
  for (int nf = 0; nf < 8; nf++) {
    int nb = wn * 128 + nf * 16 + lk * 4;
    for (int mf = 0; mf < 2; mf++) {
      int m = m0 + wm * 32 + mf * 16 + lr;
      for (int j = 0; j < 4; j++) {
        int n = nb + j;
        sup[(size_t)n * 8192 + m] = f2bf(acc[nf][mf][j] + bias[n]);
      }
    }
  }
}

// ===== Kernel 2: PRODUCER-CONSUMER. 512 thr, 1 blk/CU, NO s_barrier in loop. ====
// Wave 0: issues 32 global_load_lds/step (adj -> 4-slot x 32KB LDS ring, global
// source pre-swizzled so swizzled b128 reads are conflict-free), paced by counted
// vmcnt(36) + ring flags. Waves 0-7: poll flag, combine 4 mats in regs, MFMA.
// Slot reuse guarded by cumulative done counter (7 consumers per use).
__global__ __launch_bounds__(512, 2) void k_pc(const float* __restrict__ adj,
                                               const float* __restrict__ att,
                                               const short* __restrict__ sup,
                                               float* __restrict__ part) {
  constexpr int NSTEPS = 128;                      // kchunk 4096 / BK 32
  __shared__ __align__(16) float ring[4][8192];    // 4 slots x 32 KB (mat-major)
  __shared__ int flg[4];
  __shared__ int done[4];
  const int tid = threadIdx.x;
  const int b = blockIdx.x;
  const int xcd = b & 7;
  const int kc = xcd >> 2;                         // kc pinned per XCD group
  const int m0 = ((b >> 3) * 4 + (xcd & 3)) * 64;
  const int kbase = kc * 4096;
  const float t0 = att[0], t1 = att[1], t2 = att[2], t3 = att[3];
  const int wv = tid >> 6, lane = tid & 63;
  const int lr = lane & 15, lk = lane >> 4;
  const int swz = (lane & 7) << 4;                 // (row&7)<<4, row&7 == lane&7
  volatile int* vflg = flg;
  volatile int* vdone = done;

  if (tid < 4) { flg[tid] = 0; done[tid] = 0; }
  __syncthreads();                                 // only barrier in the kernel

  const short* sb = sup + (size_t)(wv * 64 + lr) * 8192 + kbase + lk * 8;
  f32x4 acc[4][4] = {};
  short8 af[4], afn[4];

  // producer lane geometry: instr c covers mat=c>>3, rows (c&7)*8 + (lane>>3),
  // fetching k-chunk k16=(lane&7)^(lane>>3&7) -> LDS slot (lane&7): the inverse
  // of the consumer's read swizzle (both-sides-or-neither rule).
  const int lr8 = lane >> 3, l7 = lane & 7;
  const float* pbase = adj + (size_t)(m0 + lr8) * 8192 + kbase + (l7 ^ lr8) * 4;

#define PISSUE(S, SLOT)                                                        \
  _Pragma("unroll") for (int c = 0; c < 32; c++) {                             \
    const float* g_ = pbase + (((size_t)(c >> 3)) << 26)                       \
                    + (size_t)((c & 7) * 8) * 8192 + (size_t)(S) * 32;         \
    __builtin_amdgcn_global_load_lds(                                          \
        (const __attribute__((address_space(1))) unsigned*)g_,                 \
        (__attribute__((address_space(3))) unsigned*)((char*)ring[SLOT] + c * 1024), \
        16, 0, 0);                                                             \
  }

#define LOADAF(DST, S)                                                         \
  _Pragma("unroll") for (int nf = 0; nf < 4; nf++)                             \
    DST[nf] = *(const short8*)(sb + (size_t)(nf * 16) * 8192 + (size_t)(S) * 32);

#define CONSUME(S, AFC)                                                        \
  {                                                                            \
    const char* rb_ = (const char*)ring[(S) & 3];                              \
    _Pragma("unroll") for (int mf = 0; mf < 4; mf++) {                         \
      const char* rr_ = rb_ + (mf * 16 + lr) * 128;                            \
      const int o0_ = (lk * 32) ^ swz, o1_ = (lk * 32 + 16) ^ swz;             \
      f32x4 r0a = *(const f32x4*)(rr_ + o0_);                                  \
      f32x4 r0b = *(const f32x4*)(rr_ + o1_);                                  \
      f32x4 r1a = *(const f32x4*)(rr_ + 8192 + o0_);                           \
      f32x4 r1b = *(const f32x4*)(rr_ + 8192 + o1_);                           \
      f32x4 r2a = *(const f32x4*)(rr_ + 16384 + o0_);                          \
      f32x4 r2b = *(const f32x4*)(rr_ + 16384 + o1_);                          \
      f32x4 r3a = *(const f32x4*)(rr_ + 24576 + o0_);                          \
      f32x4 r3b = *(const f32x4*)(rr_ + 24576 + o1_);                          \
      short8 bfr_;                                                             \
      _Pragma("unroll") for (int e = 0; e < 4; e++) {                          \
        bfr_[e]     = f2bf(t0 * r0a[e] + t1 * r1a[e] + t2 * r2a[e] + t3 * r3a[e]); \
        bfr_[4 + e] = f2bf(t0 * r0b[e] + t1 * r1b[e] + t2 * r2b[e] + t3 * r3b[e]); \
      }                                                                        \
      _Pragma("unroll") for (int nf = 0; nf < 4; nf++)                         \
        acc[nf][mf] = __builtin_amdgcn_mfma_f32_16x16x32_bf16(AFC[nf], bfr_,   \
                                                              acc[nf][mf], 0, 0, 0); \
    }                                                                          \
  }

  if (wv == 0) {
    // -------- producer + consumer-0 --------
    PISSUE(0, 0)
    LOADAF(af, 0)
    for (int s = 0; s < NSTEPS; s++) {
      const int sn = s + 1;
      if (sn < NSTEPS) {
        const int slot = sn & 3;
        const int need = 7 * (sn >> 2);            // waves 1-7 done with step sn-4
        while (vdone[slot] < need) __builtin_amdgcn_s_sleep(2);
        asm volatile("" ::: "memory");
        PISSUE(sn, slot)
        LOADAF(afn, sn)
        // 36 newer (PISSUE(sn)+afn) stay in flight; slot s + af(s) are complete.
        asm volatile("s_waitcnt vmcnt(36)" ::: "memory");
      } else {
        asm volatile("s_waitcnt vmcnt(0)" ::: "memory");
      }
      vflg[s & 3] = s + 1;                         // publish slot s
      asm volatile("" ::: "memory");
      CONSUME(s, af)
#pragma unroll
      for (int nf = 0; nf < 4; nf++) af[nf] = afn[nf];
    }
  } else {
    // -------- consumers 1..7 --------
    LOADAF(af, 0)
    for (int s = 0; s < NSTEPS; s++) {
      if (s + 1 < NSTEPS) LOADAF(afn, s + 1)       // in flight during the poll
      while (vflg[s & 3] != s + 1) __builtin_amdgcn_s_sleep(2);
      asm volatile("" ::: "memory");
      CONSUME(s, af)
      asm volatile("" ::: "memory");
      if (lane == 0) atomicAdd(&done[s & 3], 1);
#pragma unroll
      for (int nf = 0; nf < 4; nf++) af[nf] = afn[nf];
    }
  }

#pragma unroll
  for (int nf = 0; nf < 4; nf++) {
    int n = wv * 64 + nf * 16 + lk * 4;
#pragma unroll
    for (int mf = 0; mf < 4; mf++) {
      int m = m0 + mf * 16 + lr;
      __builtin_nontemporal_store(acc[nf][mf],
          (f32x4*)(part + ((size_t)kc << 22) + (size_t)m * 512 + n));
    }
  }
#undef PISSUE
#undef LOADAF
#undef CONSUME
}

// ==================== FALLBACK (exact R7): BM=64, ksplit<=2 ====================
#define ISSUE64(SL, S) {                                                        \
    const float* p_ = abase + (size_t)(S) * 32;                                 \
    R[SL][0] = __builtin_nontemporal_load((const f32x4*)(p_));                  \
    R[SL][1] = __builtin_nontemporal_load((const f32x4*)(p_ + (1ull << 26)));   \
    R[SL][2] = __builtin_nontemporal_load((const f32x4*)(p_ + (2ull << 26)));   \
    R[SL][3] = __builtin_nontemporal_load((const f32x4*)(p_ + (3ull << 26)));   \
  }
#define ISSUEAF64(SL, S) {                                                      \
    const short* q_ = supp + (size_t)(S) * 32;                                  \
    AF[SL][0] = *(const short8*)(q_);                                           \
    AF[SL][1] = *(const short8*)(q_ + (size_t)16 * 8192);                       \
    AF[SL][2] = *(const short8*)(q_ + (size_t)32 * 8192);                       \
    AF[SL][3] = *(const short8*)(q_ + (size_t)48 * 8192);                       \
  }
#define STEP64(U) {                                                             \
    ISSUE64(((U) + 2) & 3, (s0 + (U) + 2) & (nsteps - 1))                       \
    ISSUEAF64(((U) + 1) & 1, (s0 + (U) + 1) & (nsteps - 1))                     \
    __builtin_amdgcn_sched_barrier(0);                                          \
    asm volatile("s_waitcnt vmcnt(20)" ::: "memory");                           \
    __builtin_amdgcn_sched_barrier(0);                                          \
    f32x4 c_;                                                                   \
    _Pragma("unroll") for (int e = 0; e < 4; e++)                               \
      c_[e] = t0 * R[(U) & 3][0][e] + t1 * R[(U) & 3][1][e]                     \
            + t2 * R[(U) & 3][2][e] + t3 * R[(U) & 3][3][e];                    \
    short4t o_;                                                                 \
    _Pragma("unroll") for (int e = 0; e < 4; e++) o_[e] = f2bf(c_[e]);          \
    *(short4t*)(Bs[(U) & 1] + r * LPB + q * 4) = o_;                            \
    asm volatile("s_waitcnt lgkmcnt(0)" ::: "memory");                          \
    __builtin_amdgcn_sched_barrier(0);                                          \
    __builtin_amdgcn_s_barrier();                                               \
    __builtin_amdgcn_sched_barrier(0);                                          \
    short8 bfr[4];                                                              \
    _Pragma("unroll") for (int mf = 0; mf < 4; mf++)                            \
      bfr[mf] = *(const short8*)(Bs[(U) & 1] + (mf * 16 + lr) * LPB + lk * 8);  \
    asm volatile("s_waitcnt vmcnt(8)" ::: "memory");                            \
    __builtin_amdgcn_sched_barrier(0);                                          \
    _Pragma("unroll") for (int nf = 0; nf < 4; nf++)                            \
      _Pragma("unroll") for (int mf = 0; mf < 4; mf++)                          \
        acc[nf][mf] = __builtin_amdgcn_mfma_f32_16x16x32_bf16(AF[(U) & 1][nf],  \
                          bfr[mf], acc[nf][mf], 0, 0, 0);                       \
  }

__global__ __launch_bounds__(512, 2) void k_main64(const float* __restrict__ adj,
                                                   const float* __restrict__ att,
                                                   const short* __restrict__ sup,
                                                   float* __restrict__ part,
                                                   float* __restrict__ outp,
                                                   int ksplit) {
  __shared__ __align__(16) short Bs[2][64 * LPB];
  const int tid = threadIdx.x;
  const int b = blockIdx.x;
  const int xpk = 8 / ksplit;
  const int xcd = b & 7;
  const int kc = xcd / xpk;
  const int m0 = ((b >> 3) * xpk + (xcd % xpk)) * 64;
  const int kchunk = 8192 / ksplit;
  const int nsteps = kchunk / 32;
  const int kbase = kc * kchunk;
  const float t0 = att[0], t1 = att[1], t2 = att[2], t3 = att[3];
  const int wave = tid >> 6, lane = tid & 63;
  const int lr = lane & 15, lk = lane >> 4;
  const int r = tid >> 3, q = tid & 7;
  f32x4 acc[4][4] = {};
  const float* abase = adj + (size_t)(m0 + r) * 8192 + kbase + q * 4;
  const short* supp = sup + (size_t)(wave * 64 + lr) * 8192 + kbase + lk * 8;
  f32x4 R[4][4];
  short8 AF[2][4];
  ISSUE64(0, 0) ISSUEAF64(0, 0) ISSUE64(1, 1)
  for (int s0 = 0; s0 < nsteps; s0 += 4) {
    STEP64(0) STEP64(1) STEP64(2) STEP64(3)
  }
#pragma unroll
  for (int nf = 0; nf < 4; nf++) {
    int n = wave * 64 + nf * 16 + lk * 4;
#pragma unroll
    for (int mf = 0; mf < 4; mf++) {
      int m = m0 + mf * 16 + lr;
      f32x4 v = acc[nf][mf];
      if (ksplit == 1) {
        for (int j = 0; j < 4; j++) v[j] = lrelu(v[j]);
        __builtin_nontemporal_store(v, (f32x4*)(outp + (size_t)m * 512 + n));
      } else {
        __builtin_nontemporal_store(v, (f32x4*)(part + ((size_t)kc << 22) + (size_t)m * 512 + n));
      }
    }
  }
}

// ---------------- Kernel 3: reduce K-split partials + LeakyReLU ----------------
__global__ __launch_bounds__(256) void k_reduce(const float* __restrict__ part,
                                                float* __restrict__ outp, int ksplit) {
  const size_t total = (size_t)8192 * 512 / 4;
  for (size_t i = (size_t)blockIdx.x * 256 + threadIdx.x; i < total;
       i += (size_t)gridDim.x * 256) {
    f32x4 a = __builtin_nontemporal_load((const f32x4*)(part + i * 4));
    for (int k = 1; k < ksplit; k++) {
      f32x4 bv = __builtin_nontemporal_load((const f32x4*)(part + ((size_t)k << 22) + i * 4));
      for (int j = 0; j < 4; j++) a[j] += bv[j];
    }
    f32x4 v;
    for (int j = 0; j < 4; j++) v[j] = lrelu(a[j]);
    __builtin_nontemporal_store(v, (f32x4*)(outp + i * 4));
  }
}

extern "C" void kernel_launch(void* const* d_in, const int* in_sizes, int n_in,
                              void* d_out, int out_size, void* d_ws, size_t ws_size,
                              hipStream_t stream) {
  const float* inputs = (const float*)d_in[0];
  const float* adj    = (const float*)d_in[1];
  const float* att    = (const float*)d_in[2];
  const float* w      = (const float*)d_in[3];
  const float* bias   = (const float*)d_in[4];
  float* outp = (float*)d_out;

  char* ws = (char*)d_ws;
  short* sup  = (short*)(ws);                 // 8 MB  supportT bf16 [512][8192]
  short* wt   = (short*)(ws + (8u << 20));    // 512 KB wT bf16 [512][512]
  float* part = (float*)(ws + (9u << 20));    // ksplit x 16 MB fp32 partials

  const size_t base = (9ull << 20), psz = (1ull << 24);

  k_wt<<<64, 256, 0, stream>>>(w, wt);
  k_support<<<128, 512, 0, stream>>>(inputs, wt, bias, sup);

  if (ws_size >= base + 2 * psz) {
    // primary: producer-consumer, ksplit=2, grid 256 = 1 block/CU
    k_pc<<<256, 512, 0, stream>>>(adj, att, sup, part);
    k_reduce<<<1024, 256, 0, stream>>>(part, outp, 2);
  } else {
    k_main64<<<128, 512, 0, stream>>>(adj, att, sup, part, outp, 1);
  }
}

// Round 13
// 308.030 us; speedup vs baseline: 2.7252x; 1.1367x over previous
//
#include <hip/hip_runtime.h>

#define LP  40    // k_support LDS row stride (shorts)
#define LPB 40    // k_main Bs row stride (shorts)

typedef __attribute__((ext_vector_type(8))) short short8;
typedef __attribute__((ext_vector_type(4))) short short4t;
typedef __attribute__((ext_vector_type(4))) float f32x4;

__device__ __forceinline__ short f2bf(float f) {
  unsigned u = __builtin_bit_cast(unsigned, f);
  u += 0x7FFFu + ((u >> 16) & 1u);   // round-to-nearest-even
  return (short)(u >> 16);
}

__device__ __forceinline__ float lrelu(float v) { return v >= 0.f ? v : 0.2f * v; }

// ---------------- Kernel 0: wT bf16 [512][512]  (wt[n][c] = w[c][n]) ----------------
__global__ __launch_bounds__(256) void k_wt(const float* __restrict__ w,
                                            short* __restrict__ wt) {
  __shared__ float t[64][65];
  int c0 = (blockIdx.x & 7) * 64;
  int n0 = (blockIdx.x >> 3) * 64;
  int r  = threadIdx.x >> 4;
  int q4 = (threadIdx.x & 15) * 4;
  for (int i = 0; i < 4; i++) {
    int c = r + i * 16;
    f32x4 v = *(const f32x4*)(w + (size_t)(c0 + c) * 512 + (n0 + q4));
    t[c][q4 + 0] = v[0]; t[c][q4 + 1] = v[1]; t[c][q4 + 2] = v[2]; t[c][q4 + 3] = v[3];
  }
  __syncthreads();
  for (int i = 0; i < 4; i++) {
    int n = r + i * 16;
    short4t o;
    for (int j = 0; j < 4; j++) o[j] = f2bf(t[q4 + j][n]);
    *(short4t*)(wt + (size_t)(n0 + n) * 512 + (c0 + q4)) = o;
  }
}

// ------------- Kernel 1: supportT bf16 [512][8192] = (inputs @ w + b)^T -------------
__global__ __launch_bounds__(512, 2) void k_support(const float* __restrict__ inp,
                                                    const short* __restrict__ wt,
                                                    const float* __restrict__ bias,
                                                    short* __restrict__ sup) {
  __shared__ __align__(16) short As[512 * LP];
  __shared__ __align__(16) short Bs[64 * LP];
  const int tid = threadIdx.x;
  const int m0 = blockIdx.x * 64;
  const int wave = tid >> 6, lane = tid & 63;
  const int wn = wave >> 1, wm = wave & 1;
  const int lr = lane & 15, lk = lane >> 4;
  const int bm = tid >> 3, bk = (tid & 7) * 4;
  f32x4 acc[8][2] = {};
  short8 ar[4]; f32x4 br;
  auto loadA = [&](int s) {
    const short* p = wt + (size_t)tid * 512 + s * 32;
    ar[0] = *(const short8*)(p);      ar[1] = *(const short8*)(p + 8);
    ar[2] = *(const short8*)(p + 16); ar[3] = *(const short8*)(p + 24);
  };
  auto loadB = [&](int s) {
    br = *(const f32x4*)(inp + (size_t)(m0 + bm) * 512 + s * 32 + bk);
  };
  loadA(0); loadB(0);
  for (int s = 0; s < 16; s++) {
    short* ad = As + tid * LP;
    *(short8*)(ad) = ar[0]; *(short8*)(ad + 8) = ar[1];
    *(short8*)(ad + 16) = ar[2]; *(short8*)(ad + 24) = ar[3];
    short4t bo;
    for (int j = 0; j < 4; j++) bo[j] = f2bf(br[j]);
    *(short4t*)(Bs + bm * LP + bk) = bo;
    __syncthreads();
    if (s + 1 < 16) { loadA(s + 1); loadB(s + 1); }
    short8 af[8], bfr[2];
    for (int nf = 0; nf < 8; nf++)
      af[nf] = *(const short8*)(As + (wn * 128 + nf * 16 + lr) * LP + lk * 8);
    for (int mf = 0; mf < 2; mf++)
      bfr[mf] = *(const short8*)(Bs + (wm * 32 + mf * 16 + lr) * LP + lk * 8);
    for (int nf = 0; nf < 8; nf++)
      for (int mf = 0; mf < 2; mf++)
        acc[nf][mf] = __builtin_amdgcn_mfma_f32_16x16x32_bf16(af[nf], bfr[mf], acc[nf][mf], 0, 0, 0);
    __syncthreads();
  }
  for (int nf = 0; nf < 8; nf++) {
    int nb = wn * 128 + nf * 16 + lk * 4;
    for (int mf = 0; mf < 2; mf++) {
      int m = m0 + wm * 32 + mf * 16 + lr;
      for (int j = 0; j < 4; j++) {
        int n = nb + j;
        sup[(size_t)n * 8192 + m] = f2bf(acc[nf][mf][j] + bias[n]);
      }
    }
  }
}

// ---- Kernel 2 (exact R7 best: 308 us total): BM=64, BN=512, BK=32, drain-free
// ---- barrier (lgkmcnt(0)-only s_barrier), dist-2 adj + dist-1 af reg prefetch,
// ---- counted vmcnt pacing, wrap-around dummy issues for uniform FIFO counts.
#define ISSUE(SL, S) {                                                          \
    const float* p_ = abase + (size_t)(S) * 32;                                 \
    R[SL][0] = __builtin_nontemporal_load((const f32x4*)(p_));                  \
    R[SL][1] = __builtin_nontemporal_load((const f32x4*)(p_ + (1ull << 26)));   \
    R[SL][2] = __builtin_nontemporal_load((const f32x4*)(p_ + (2ull << 26)));   \
    R[SL][3] = __builtin_nontemporal_load((const f32x4*)(p_ + (3ull << 26)));   \
  }

#define ISSUEAF(SL, S) {                                                        \
    const short* q_ = supp + (size_t)(S) * 32;                                  \
    AF[SL][0] = *(const short8*)(q_);                                           \
    AF[SL][1] = *(const short8*)(q_ + (size_t)16 * 8192);                       \
    AF[SL][2] = *(const short8*)(q_ + (size_t)32 * 8192);                       \
    AF[SL][3] = *(const short8*)(q_ + (size_t)48 * 8192);                       \
  }

#define STEP(U) {                                                               \
    ISSUE(((U) + 2) & 3, (s0 + (U) + 2) & (nsteps - 1))                         \
    ISSUEAF(((U) + 1) & 1, (s0 + (U) + 1) & (nsteps - 1))                       \
    __builtin_amdgcn_sched_barrier(0);                                          \
    asm volatile("s_waitcnt vmcnt(20)" ::: "memory");                           \
    __builtin_amdgcn_sched_barrier(0);                                          \
    f32x4 c_;                                                                   \
    _Pragma("unroll") for (int e = 0; e < 4; e++)                               \
      c_[e] = t0 * R[(U) & 3][0][e] + t1 * R[(U) & 3][1][e]                     \
            + t2 * R[(U) & 3][2][e] + t3 * R[(U) & 3][3][e];                    \
    short4t o_;                                                                 \
    _Pragma("unroll") for (int e = 0; e < 4; e++) o_[e] = f2bf(c_[e]);          \
    *(short4t*)(Bs[(U) & 1] + r * LPB + q * 4) = o_;                            \
    asm volatile("s_waitcnt lgkmcnt(0)" ::: "memory");                          \
    __builtin_amdgcn_sched_barrier(0);                                          \
    __builtin_amdgcn_s_barrier();                                               \
    __builtin_amdgcn_sched_barrier(0);                                          \
    short8 bfr[4];                                                              \
    _Pragma("unroll") for (int mf = 0; mf < 4; mf++)                            \
      bfr[mf] = *(const short8*)(Bs[(U) & 1] + (mf * 16 + lr) * LPB + lk * 8);  \
    asm volatile("s_waitcnt vmcnt(8)" ::: "memory");                            \
    __builtin_amdgcn_sched_barrier(0);                                          \
    _Pragma("unroll") for (int nf = 0; nf < 4; nf++)                            \
      _Pragma("unroll") for (int mf = 0; mf < 4; mf++)                          \
        acc[nf][mf] = __builtin_amdgcn_mfma_f32_16x16x32_bf16(AF[(U) & 1][nf],  \
                          bfr[mf], acc[nf][mf], 0, 0, 0);                       \
  }

__global__ __launch_bounds__(512, 2) void k_main(const float* __restrict__ adj,
                                                 const float* __restrict__ att,
                                                 const short* __restrict__ sup,
                                                 float* __restrict__ part,
                                                 float* __restrict__ outp,
                                                 int ksplit) {
  __shared__ __align__(16) short Bs[2][64 * LPB];
  const int tid = threadIdx.x;
  const int b = blockIdx.x;
  const int xpk = 8 / ksplit;
  const int xcd = b & 7;
  const int kc = xcd / xpk;                 // kc pinned per XCD group -> sup L2-warm
  const int m0 = ((b >> 3) * xpk + (xcd % xpk)) * 64;
  const int kchunk = 8192 / ksplit;
  const int nsteps = kchunk / 32;           // 128 at ksplit=2 (pow2)
  const int kbase = kc * kchunk;
  const float t0 = att[0], t1 = att[1], t2 = att[2], t3 = att[3];
  const int wave = tid >> 6, lane = tid & 63;
  const int lr = lane & 15, lk = lane >> 4;
  const int r = tid >> 3, q = tid & 7;      // combine map: row 0..63, 16B-octant
  f32x4 acc[4][4] = {};                     // [nf][mf]
  const float* abase = adj + (size_t)(m0 + r) * 8192 + kbase + q * 4;
  const short* supp = sup + (size_t)(wave * 64 + lr) * 8192 + kbase + lk * 8;
  f32x4 R[4][4];                            // adj slots (distance 2)
  short8 AF[2][4];                          // sup slots (distance 1)

  ISSUE(0, 0) ISSUEAF(0, 0) ISSUE(1, 1)
  for (int s0 = 0; s0 < nsteps; s0 += 4) {
    STEP(0) STEP(1) STEP(2) STEP(3)
  }

#pragma unroll
  for (int nf = 0; nf < 4; nf++) {
    int n = wave * 64 + nf * 16 + lk * 4;
#pragma unroll
    for (int mf = 0; mf < 4; mf++) {
      int m = m0 + mf * 16 + lr;
      f32x4 v = acc[nf][mf];
      if (ksplit == 1) {
        for (int j = 0; j < 4; j++) v[j] = lrelu(v[j]);
        __builtin_nontemporal_store(v, (f32x4*)(outp + (size_t)m * 512 + n));
      } else {
        __builtin_nontemporal_store(v, (f32x4*)(part + ((size_t)kc << 22) + (size_t)m * 512 + n));
      }
    }
  }
}

// ---------------- Kernel 3: reduce K-split partials + LeakyReLU ----------------
__global__ __launch_bounds__(256) void k_reduce(const float* __restrict__ part,
                                                float* __restrict__ outp, int ksplit) {
  const size_t total = (size_t)8192 * 512 / 4;
  for (size_t i = (size_t)blockIdx.x * 256 + threadIdx.x; i < total;
       i += (size_t)gridDim.x * 256) {
    f32x4 a = __builtin_nontemporal_load((const f32x4*)(part + i * 4));
    for (int k = 1; k < ksplit; k++) {
      f32x4 bv = __builtin_nontemporal_load((const f32x4*)(part + ((size_t)k << 22) + i * 4));
      for (int j = 0; j < 4; j++) a[j] += bv[j];
    }
    f32x4 v;
    for (int j = 0; j < 4; j++) v[j] = lrelu(a[j]);
    __builtin_nontemporal_store(v, (f32x4*)(outp + i * 4));
  }
}

extern "C" void kernel_launch(void* const* d_in, const int* in_sizes, int n_in,
                              void* d_out, int out_size, void* d_ws, size_t ws_size,
                              hipStream_t stream) {
  const float* inputs = (const float*)d_in[0];
  const float* adj    = (const float*)d_in[1];
  const float* att    = (const float*)d_in[2];
  const float* w      = (const float*)d_in[3];
  const float* bias   = (const float*)d_in[4];
  float* outp = (float*)d_out;

  char* ws = (char*)d_ws;
  short* sup  = (short*)(ws);                 // 8 MB  supportT bf16 [512][8192]
  short* wt   = (short*)(ws + (8u << 20));    // 512 KB wT bf16 [512][512]
  float* part = (float*)(ws + (9u << 20));    // ksplit x 16 MB fp32 partials

  const size_t base = (9ull << 20), psz = (1ull << 24);
  int ksplit = (ws_size >= base + 2 * psz) ? 2 : 1;

  k_wt<<<64, 256, 0, stream>>>(w, wt);
  k_support<<<128, 512, 0, stream>>>(inputs, wt, bias, sup);
  k_main<<<128 * ksplit, 512, 0, stream>>>(adj, att, sup, part, outp, ksplit);
  if (ksplit > 1) k_reduce<<<1024, 256, 0, stream>>>(part, outp, ksplit);
}